// Round 4
// baseline (137.254 us; speedup 1.0000x reference)
//
#include <hip/hip_runtime.h>
#include <math.h>

// Problem constants (match reference)
#define NXC 1024
#define NYC 1024
#define DC  128
#define NCM1 4
#define NBLK 256   // 16x16 tiles of 64x64; == #CUs so all blocks co-resident

// ws float offsets
#define WS_ROWPM 0        // 1024*16  per-tile row partial max   [row][tile]
#define WS_ROWPL 16384    // 1024*16  per-tile row partial sumexp
#define WS_COLPM 32768    // 1024*16
#define WS_COLPL 49152    // 1024*16
#define WS_PART0 65536    // 256 per-block S0
#define WS_PART1 65792    // 256 per-block S1
#define WS_FLAG1 66048    // 256 ints (barrier 1 flags; poison 0xAA != 1)
#define WS_FLAG2 66304    // 256 ints (barrier 2 flags)

typedef _Float16 half2v __attribute__((ext_vector_type(2)));
union H2U { half2v h; unsigned u; };

#if defined(__has_builtin)
#if __has_builtin(__builtin_amdgcn_fdot2)
#define HAVE_FDOT2 1
#endif
#endif

// |xa - ya| summed into f32 acc, 8 halves (one 16B chunk) at a time.
__device__ __forceinline__ float absdiff_dot(uint4 xa, uint4 ya, float acc)
{
    const unsigned* xu = (const unsigned*)&xa;
    const unsigned* yu = (const unsigned*)&ya;
    half2v one; one.x = (_Float16)1.f; one.y = (_Float16)1.f;
    #pragma unroll
    for (int q = 0; q < 4; ++q) {
        H2U x, y, d;
        x.u = xu[q]; y.u = yu[q];
        d.h = x.h - y.h;              // v_pk_add_f16 (neg)
        d.u &= 0x7FFF7FFFu;           // packed abs
#ifdef HAVE_FDOT2
        acc = __builtin_amdgcn_fdot2(d.h, one, acc, false);  // v_dot2_f32_f16
#else
        acc += (float)d.h.x + (float)d.h.y;
#endif
    }
    return acc;
}

// -------------------------------------------------------------------------
// Single persistent kernel. 256 blocks (1/CU) x 512 threads (8 waves/CU).
// Block = 64x64 tile of s; 2x4 micro-tile per thread held in registers.
// fp16 staging in LDS (16B chunks, XOR swizzle j^((r>>2)&7) -> <=2-way).
// Grid barriers via per-block flag arrays (no init dispatch needed: the
// harness poisons ws with 0xAA which != the flag value 1).
// -------------------------------------------------------------------------
__global__ __launch_bounds__(512) void fused_kernel(
    const float* __restrict__ zx, const float* __restrict__ zy,
    const float* __restrict__ theta, const float* __restrict__ beta,
    float* __restrict__ ws, float* __restrict__ out)
{
    __shared__ __align__(16) _Float16 xs[64 * 128];
    __shared__ __align__(16) _Float16 ys[64 * 128];
    __shared__ float cpm[32][64], cpl[32][64];
    __shared__ float rm_s[64], rl_s[64], cm_s[64], cl_s[64];
    __shared__ float red0[8], red1[8];

    float* rowp_m = ws + WS_ROWPM;
    float* rowp_l = ws + WS_ROWPL;
    float* colp_m = ws + WS_COLPM;
    float* colp_l = ws + WS_COLPL;
    float* part0  = ws + WS_PART0;
    float* part1  = ws + WS_PART1;
    int*   flag1  = (int*)ws + WS_FLAG1;
    int*   flag2  = (int*)ws + WS_FLAG2;

    const int t  = threadIdx.x;
    const int bx = blockIdx.x & 15;   // col-tile index
    const int by = blockIdx.x >> 4;   // row-tile index
    const int x0 = by * 64;
    const int y0 = bx * 64;

    // ---- Phase 1a: stage 64x128 of zx, zy into LDS as fp16 (RNE casts) ----
    #pragma unroll
    for (int k = 0; k < 2; ++k) {
        int idx = t + k * 512;        // half8-chunk index: 64 rows x 16 chunks
        int r   = idx >> 4;
        int j   = idx & 15;
        int off = r * 128 + 8 * (j ^ ((r >> 2) & 7));

        const float4* gx = (const float4*)(zx + (size_t)(x0 + r) * DC + 8 * j);
        float4 xv0 = gx[0], xv1 = gx[1];
        const float4* gy = (const float4*)(zy + (size_t)(y0 + r) * DC + 8 * j);
        float4 yv0 = gy[0], yv1 = gy[1];

        uint4 hx, hy;
        {
            H2U a, b, c, d;
            a.h.x = (_Float16)xv0.x; a.h.y = (_Float16)xv0.y;
            b.h.x = (_Float16)xv0.z; b.h.y = (_Float16)xv0.w;
            c.h.x = (_Float16)xv1.x; c.h.y = (_Float16)xv1.y;
            d.h.x = (_Float16)xv1.z; d.h.y = (_Float16)xv1.w;
            hx.x = a.u; hx.y = b.u; hx.z = c.u; hx.w = d.u;
            a.h.x = (_Float16)yv0.x; a.h.y = (_Float16)yv0.y;
            b.h.x = (_Float16)yv0.z; b.h.y = (_Float16)yv0.w;
            c.h.x = (_Float16)yv1.x; c.h.y = (_Float16)yv1.y;
            d.h.x = (_Float16)yv1.z; d.h.y = (_Float16)yv1.w;
            hy.x = a.u; hy.y = b.u; hy.z = c.u; hy.w = d.u;
        }
        *(uint4*)(xs + off) = hx;
        *(uint4*)(ys + off) = hy;
    }
    __syncthreads();

    const int tx = t & 15;            // 4 cols each
    const int ty = t >> 4;            // 0..31, 2 rows each
    const int xswz = (ty >> 1) & 7;   // == ((2ty+i)>>2)&7 for i in {0,1}
    const int yswz = tx & 7;          // == ((4tx+jj)>>2)&7 for jj in {0..3}

    const _Float16* xb = xs + (2 * ty) * 128;
    const _Float16* yb = ys + (4 * tx) * 128;

    // ---- Phase 1b: 2x4 micro-tile L1 distances (fp16 diffs, f32 acc) ----
    float acc[2][4];
    #pragma unroll
    for (int i = 0; i < 2; ++i)
        #pragma unroll
        for (int j = 0; j < 4; ++j) acc[i][j] = 0.f;

    #pragma unroll 4
    for (int j = 0; j < 16; ++j) {    // 16 chunks of 8 d-values
        uint4 xc0 = *(const uint4*)(xb + 8 * (j ^ xswz));
        uint4 xc1 = *(const uint4*)(xb + 128 + 8 * (j ^ xswz));
        uint4 yc0 = *(const uint4*)(yb + 8 * (j ^ yswz));
        uint4 yc1 = *(const uint4*)(yb + 128 + 8 * (j ^ yswz));
        uint4 yc2 = *(const uint4*)(yb + 256 + 8 * (j ^ yswz));
        uint4 yc3 = *(const uint4*)(yb + 384 + 8 * (j ^ yswz));

        acc[0][0] = absdiff_dot(xc0, yc0, acc[0][0]);
        acc[0][1] = absdiff_dot(xc0, yc1, acc[0][1]);
        acc[0][2] = absdiff_dot(xc0, yc2, acc[0][2]);
        acc[0][3] = absdiff_dot(xc0, yc3, acc[0][3]);
        acc[1][0] = absdiff_dot(xc1, yc0, acc[1][0]);
        acc[1][1] = absdiff_dot(xc1, yc1, acc[1][1]);
        acc[1][2] = absdiff_dot(xc1, yc2, acc[1][2]);
        acc[1][3] = absdiff_dot(xc1, yc3, acc[1][3]);
    }

    float sv[2][4];
    #pragma unroll
    for (int i = 0; i < 2; ++i)
        #pragma unroll
        for (int j = 0; j < 4; ++j) sv[i][j] = -acc[i][j];

    // ---- Phase 1c: per-tile ROW partials (merge across tx, in-wave) ----
    #pragma unroll
    for (int i = 0; i < 2; ++i) {
        float m = fmaxf(fmaxf(sv[i][0], sv[i][1]), fmaxf(sv[i][2], sv[i][3]));
        float l = __expf(sv[i][0] - m) + __expf(sv[i][1] - m)
                + __expf(sv[i][2] - m) + __expf(sv[i][3] - m);
        #pragma unroll
        for (int off = 1; off < 16; off <<= 1) {
            float mo = __shfl_xor(m, off, 64);
            float lo = __shfl_xor(l, off, 64);
            float nm = fmaxf(m, mo);
            l = l * __expf(m - nm) + lo * __expf(mo - nm);
            m = nm;
        }
        if (tx == 0) {
            rowp_m[(size_t)(x0 + 2 * ty + i) * 16 + bx] = m;
            rowp_l[(size_t)(x0 + 2 * ty + i) * 16 + bx] = l;
        }
    }

    // ---- Phase 1d: per-tile COL partials (merge across ty via LDS) ----
    #pragma unroll
    for (int j = 0; j < 4; ++j) {
        float m = fmaxf(sv[0][j], sv[1][j]);
        float l = __expf(sv[0][j] - m) + __expf(sv[1][j] - m);
        cpm[ty][4 * tx + j] = m;
        cpl[ty][4 * tx + j] = l;
    }
    __syncthreads();
    if (t < 64) {
        float m = cpm[0][t], l = cpl[0][t];
        #pragma unroll 8
        for (int k = 1; k < 32; ++k) {
            float mo = cpm[k][t], lo = cpl[k][t];
            float nm = fmaxf(m, mo);
            l = l * __expf(m - nm) + lo * __expf(mo - nm);
            m = nm;
        }
        colp_m[(size_t)(y0 + t) * 16 + by] = m;
        colp_l[(size_t)(y0 + t) * 16 + by] = l;
    }

    // ---- Grid barrier 1: publish flags, poll all 256 ----
    __syncthreads();
    if (t == 0) {
        __threadfence();
        __hip_atomic_store(&flag1[blockIdx.x], 1, __ATOMIC_RELEASE, __HIP_MEMORY_SCOPE_AGENT);
    }
    if (t < NBLK) {
        while (__hip_atomic_load(&flag1[t], __ATOMIC_ACQUIRE, __HIP_MEMORY_SCOPE_AGENT) != 1)
            __builtin_amdgcn_s_sleep(2);
    }
    __syncthreads();
    __threadfence();

    // ---- Phase 2: combine 16 tile-partials for this tile's rows & cols ----
    if (t < 64) {
        const size_t i = (size_t)(x0 + t) * 16;
        float m = rowp_m[i], l = rowp_l[i];
        #pragma unroll
        for (int k = 1; k < 16; ++k) {
            float mo = rowp_m[i + k], lo = rowp_l[i + k];
            float nm = fmaxf(m, mo);
            l = l * __expf(m - nm) + lo * __expf(mo - nm);
            m = nm;
        }
        rm_s[t] = m; rl_s[t] = 1.f / l;
    } else if (t < 128) {
        const size_t c = (size_t)(y0 + (t - 64)) * 16;
        float m = colp_m[c], l = colp_l[c];
        #pragma unroll
        for (int k = 1; k < 16; ++k) {
            float mo = colp_m[c + k], lo = colp_l[c + k];
            float nm = fmaxf(m, mo);
            l = l * __expf(m - nm) + lo * __expf(mo - nm);
            m = nm;
        }
        cm_s[t - 64] = m; cl_s[t - 64] = 1.f / l;
    }
    __syncthreads();

    // ---- Phase 3: weighted reduction from registers ----
    float S0 = 0.f, S1 = 0.f;
    #pragma unroll
    for (int i = 0; i < 2; ++i) {
        const float rm = rm_s[2 * ty + i];
        const float rl = rl_s[2 * ty + i];
        #pragma unroll
        for (int j = 0; j < 4; ++j) {
            const float cm = cm_s[4 * tx + j];
            const float cl = cl_s[4 * tx + j];
            float s = sv[i][j];
            float a = __expf(s - rm) * rl;
            float b = __expf(s - cm) * cl;
            float w = a + b - a * b;
            S0 += w;
            S1 += w * s;
        }
    }
    #pragma unroll
    for (int off = 32; off; off >>= 1) {
        S0 += __shfl_xor(S0, off, 64);
        S1 += __shfl_xor(S1, off, 64);
    }
    {
        const int wave = t >> 6, lane = t & 63;
        if (lane == 0) { red0[wave] = S0; red1[wave] = S1; }
    }
    __syncthreads();
    if (t == 0) {
        float t0 = 0.f, t1 = 0.f;
        #pragma unroll
        for (int w = 0; w < 8; ++w) { t0 += red0[w]; t1 += red1[w]; }
        part0[blockIdx.x] = t0;
        part1[blockIdx.x] = t1;
        __threadfence();
        __hip_atomic_store(&flag2[blockIdx.x], 1, __ATOMIC_RELEASE, __HIP_MEMORY_SCOPE_AGENT);
    }

    // ---- Finalize: block 0 waits on all flag2, sums parts, writes logits ----
    if (blockIdx.x == 0) {
        if (t < NBLK) {
            while (__hip_atomic_load(&flag2[t], __ATOMIC_ACQUIRE, __HIP_MEMORY_SCOPE_AGENT) != 1)
                __builtin_amdgcn_s_sleep(2);
        }
        __syncthreads();
        __threadfence();

        float S0f = 0.f, S1f = 0.f;
        if (t < NBLK) { S0f = part0[t]; S1f = part1[t]; }
        #pragma unroll
        for (int off = 32; off; off >>= 1) {
            S0f += __shfl_xor(S0f, off, 64);
            S1f += __shfl_xor(S1f, off, 64);
        }
        {
            const int wave = t >> 6, lane = t & 63;
            if (lane == 0) { red0[wave] = S0f; red1[wave] = S1f; }
        }
        __syncthreads();
        if (t < NCM1) {
            float t0 = red0[0] + red0[1] + red0[2] + red0[3];
            float t1 = red1[0] + red1[1] + red1[2] + red1[3];
            float c = t1 / t0;
            out[t] = c * theta[t] + beta[t];
        }
    }
}

// -------------------------------------------------------------------------
extern "C" void kernel_launch(void* const* d_in, const int* in_sizes, int n_in,
                              void* d_out, int out_size, void* d_ws, size_t ws_size,
                              hipStream_t stream)
{
    const float* zx    = (const float*)d_in[0];
    const float* zy    = (const float*)d_in[1];
    const float* theta = (const float*)d_in[2];
    const float* beta  = (const float*)d_in[3];
    float* out = (float*)d_out;
    float* ws  = (float*)d_ws;

    fused_kernel<<<NBLK, 512, 0, stream>>>(zx, zy, theta, beta, ws, out);
}

// Round 5
// 115.363 us; speedup vs baseline: 1.1898x; 1.1898x over previous
//
#include <hip/hip_runtime.h>
#include <math.h>

// Problem constants (match reference)
#define NXC 1024
#define NYC 1024
#define DC  128
#define NCM1 4
#define NBLK 256   // 16x16 tiles of 64x64; == #CUs so all blocks co-resident

// ws float offsets (float2-packed partials; 8B aligned)
#define WS_ROWP  0        // float2[1024][16]  (m,l) row partials  -> 32768 floats
#define WS_COLP  32768    // float2[1024][16]  (m,l) col partials  -> 32768 floats
#define WS_PART  65536    // float2[256]       (S0,S1) block parts ->   512 floats
// int offsets into (int*)ws
#define WS_FLAG1 66048    // 256 ints (poison 0xAAAAAAAA != 1 -> no init needed)
#define WS_FLAG2 66304    // 256 ints

typedef _Float16 half2v __attribute__((ext_vector_type(2)));
union H2U { half2v h; unsigned u; };
union F2U { float2 f; unsigned long long u; };

#if defined(__has_builtin)
#if __has_builtin(__builtin_amdgcn_fdot2)
#define HAVE_FDOT2 1
#endif
#endif

// |xa - ya| summed into f32 acc, 8 halves (one 16B chunk) at a time.
__device__ __forceinline__ float absdiff_dot(uint4 xa, uint4 ya, float acc)
{
    const unsigned* xu = (const unsigned*)&xa;
    const unsigned* yu = (const unsigned*)&ya;
    half2v one; one.x = (_Float16)1.f; one.y = (_Float16)1.f;
    #pragma unroll
    for (int q = 0; q < 4; ++q) {
        H2U x, y, d;
        x.u = xu[q]; y.u = yu[q];
        d.h = x.h - y.h;              // v_pk_add_f16 (neg)
        d.u &= 0x7FFF7FFFu;           // packed abs
#ifdef HAVE_FDOT2
        acc = __builtin_amdgcn_fdot2(d.h, one, acc, false);  // v_dot2_f32_f16
#else
        acc += (float)d.h.x + (float)d.h.y;
#endif
    }
    return acc;
}

// relaxed agent-scope 64-bit accessors (coherence-point, NO cache maintenance)
__device__ __forceinline__ void store_f2(float* p, float m, float l) {
    F2U u; u.f.x = m; u.f.y = l;
    __hip_atomic_store((unsigned long long*)p, u.u, __ATOMIC_RELAXED, __HIP_MEMORY_SCOPE_AGENT);
}
__device__ __forceinline__ float2 load_f2(const float* p) {
    F2U u;
    u.u = __hip_atomic_load((const unsigned long long*)p, __ATOMIC_RELAXED, __HIP_MEMORY_SCOPE_AGENT);
    return u.f;
}

// -------------------------------------------------------------------------
// Single persistent kernel. 256 blocks (1/CU) x 512 threads (2 waves/SIMD).
// Block = 64x64 tile of s; 2x4 micro-tile per thread held in registers.
// fp16 staging in LDS (16B chunks, XOR swizzle -> <=2-way, free per m136).
// Grid barrier: per-block flags; RELAXED polling (no buffer_inv storm),
// one RELEASE flag-store + one __threadfence per block.
// -------------------------------------------------------------------------
__global__ __launch_bounds__(512, 2) void fused_kernel(
    const float* __restrict__ zx, const float* __restrict__ zy,
    const float* __restrict__ theta, const float* __restrict__ beta,
    float* __restrict__ ws, float* __restrict__ out)
{
    __shared__ __align__(16) _Float16 xs[64 * 128];
    __shared__ __align__(16) _Float16 ys[64 * 128];
    __shared__ float cpm[32][64], cpl[32][64];
    __shared__ float rm_s[64], rl_s[64], cm_s[64], cl_s[64];
    __shared__ float red0[8], red1[8];

    float* rowp  = ws + WS_ROWP;
    float* colp  = ws + WS_COLP;
    float* part  = ws + WS_PART;
    int*   flag1 = (int*)ws + WS_FLAG1;
    int*   flag2 = (int*)ws + WS_FLAG2;

    const int t  = threadIdx.x;
    const int bx = blockIdx.x & 15;   // col-tile index
    const int by = blockIdx.x >> 4;   // row-tile index
    const int x0 = by * 64;
    const int y0 = bx * 64;

    // ---- Phase 1a: stage 64x128 of zx, zy into LDS as fp16 (RNE casts) ----
    #pragma unroll
    for (int k = 0; k < 2; ++k) {
        int idx = t + k * 512;        // half8-chunk index: 64 rows x 16 chunks
        int r   = idx >> 4;
        int j   = idx & 15;
        int off = r * 128 + 8 * (j ^ ((r >> 2) & 7));

        const float4* gx = (const float4*)(zx + (size_t)(x0 + r) * DC + 8 * j);
        float4 xv0 = gx[0], xv1 = gx[1];
        const float4* gy = (const float4*)(zy + (size_t)(y0 + r) * DC + 8 * j);
        float4 yv0 = gy[0], yv1 = gy[1];

        uint4 hx, hy;
        {
            H2U a, b, c, d;
            a.h.x = (_Float16)xv0.x; a.h.y = (_Float16)xv0.y;
            b.h.x = (_Float16)xv0.z; b.h.y = (_Float16)xv0.w;
            c.h.x = (_Float16)xv1.x; c.h.y = (_Float16)xv1.y;
            d.h.x = (_Float16)xv1.z; d.h.y = (_Float16)xv1.w;
            hx.x = a.u; hx.y = b.u; hx.z = c.u; hx.w = d.u;
            a.h.x = (_Float16)yv0.x; a.h.y = (_Float16)yv0.y;
            b.h.x = (_Float16)yv0.z; b.h.y = (_Float16)yv0.w;
            c.h.x = (_Float16)yv1.x; c.h.y = (_Float16)yv1.y;
            d.h.x = (_Float16)yv1.z; d.h.y = (_Float16)yv1.w;
            hy.x = a.u; hy.y = b.u; hy.z = c.u; hy.w = d.u;
        }
        *(uint4*)(xs + off) = hx;
        *(uint4*)(ys + off) = hy;
    }
    __syncthreads();

    const int tx = t & 15;            // 4 cols each
    const int ty = t >> 4;            // 0..31, 2 rows each
    const int xswz = (ty >> 1) & 7;
    const int yswz = tx & 7;

    const _Float16* xb = xs + (2 * ty) * 128;
    const _Float16* yb = ys + (4 * tx) * 128;

    // ---- Phase 1b: 2x4 micro-tile L1 distances, distance-1 prefetch ----
    float acc[2][4];
    #pragma unroll
    for (int i = 0; i < 2; ++i)
        #pragma unroll
        for (int j = 0; j < 4; ++j) acc[i][j] = 0.f;

    uint4 xc0 = *(const uint4*)(xb +       8 * (0 ^ xswz));
    uint4 xc1 = *(const uint4*)(xb + 128 + 8 * (0 ^ xswz));
    uint4 yc0 = *(const uint4*)(yb +       8 * (0 ^ yswz));
    uint4 yc1 = *(const uint4*)(yb + 128 + 8 * (0 ^ yswz));
    uint4 yc2 = *(const uint4*)(yb + 256 + 8 * (0 ^ yswz));
    uint4 yc3 = *(const uint4*)(yb + 384 + 8 * (0 ^ yswz));

    #pragma unroll 4
    for (int j = 0; j < 16; ++j) {
        uint4 xa0 = xc0, xa1 = xc1, ya0 = yc0, ya1 = yc1, ya2 = yc2, ya3 = yc3;
        if (j < 15) {
            const int jn = j + 1;
            xc0 = *(const uint4*)(xb +       8 * (jn ^ xswz));
            xc1 = *(const uint4*)(xb + 128 + 8 * (jn ^ xswz));
            yc0 = *(const uint4*)(yb +       8 * (jn ^ yswz));
            yc1 = *(const uint4*)(yb + 128 + 8 * (jn ^ yswz));
            yc2 = *(const uint4*)(yb + 256 + 8 * (jn ^ yswz));
            yc3 = *(const uint4*)(yb + 384 + 8 * (jn ^ yswz));
        }
        acc[0][0] = absdiff_dot(xa0, ya0, acc[0][0]);
        acc[0][1] = absdiff_dot(xa0, ya1, acc[0][1]);
        acc[0][2] = absdiff_dot(xa0, ya2, acc[0][2]);
        acc[0][3] = absdiff_dot(xa0, ya3, acc[0][3]);
        acc[1][0] = absdiff_dot(xa1, ya0, acc[1][0]);
        acc[1][1] = absdiff_dot(xa1, ya1, acc[1][1]);
        acc[1][2] = absdiff_dot(xa1, ya2, acc[1][2]);
        acc[1][3] = absdiff_dot(xa1, ya3, acc[1][3]);
    }

    float sv[2][4];
    #pragma unroll
    for (int i = 0; i < 2; ++i)
        #pragma unroll
        for (int j = 0; j < 4; ++j) sv[i][j] = -acc[i][j];

    // ---- Phase 1c: per-tile ROW partials (merge across tx, in-wave) ----
    #pragma unroll
    for (int i = 0; i < 2; ++i) {
        float m = fmaxf(fmaxf(sv[i][0], sv[i][1]), fmaxf(sv[i][2], sv[i][3]));
        float l = __expf(sv[i][0] - m) + __expf(sv[i][1] - m)
                + __expf(sv[i][2] - m) + __expf(sv[i][3] - m);
        #pragma unroll
        for (int off = 1; off < 16; off <<= 1) {
            float mo = __shfl_xor(m, off, 64);
            float lo = __shfl_xor(l, off, 64);
            float nm = fmaxf(m, mo);
            l = l * __expf(m - nm) + lo * __expf(mo - nm);
            m = nm;
        }
        if (tx == 0)
            store_f2(rowp + 2 * ((size_t)(x0 + 2 * ty + i) * 16 + bx), m, l);
    }

    // ---- Phase 1d: per-tile COL partials (merge across ty via LDS) ----
    #pragma unroll
    for (int j = 0; j < 4; ++j) {
        float m = fmaxf(sv[0][j], sv[1][j]);
        float l = __expf(sv[0][j] - m) + __expf(sv[1][j] - m);
        cpm[ty][4 * tx + j] = m;
        cpl[ty][4 * tx + j] = l;
    }
    __syncthreads();
    if (t < 64) {
        float m = cpm[0][t], l = cpl[0][t];
        #pragma unroll 8
        for (int k = 1; k < 32; ++k) {
            float mo = cpm[k][t], lo = cpl[k][t];
            float nm = fmaxf(m, mo);
            l = l * __expf(m - nm) + lo * __expf(mo - nm);
            m = nm;
        }
        store_f2(colp + 2 * ((size_t)(y0 + t) * 16 + by), m, l);
    }

    // ---- Grid barrier 1: one RELEASE store, RELAXED polling ----
    __syncthreads();
    if (t == 0)
        __hip_atomic_store(&flag1[blockIdx.x], 1, __ATOMIC_RELEASE, __HIP_MEMORY_SCOPE_AGENT);
    if (t < NBLK) {
        while (__hip_atomic_load(&flag1[t], __ATOMIC_RELAXED, __HIP_MEMORY_SCOPE_AGENT) != 1)
            __builtin_amdgcn_s_sleep(8);
    }
    __threadfence();
    __syncthreads();

    // ---- Phase 2: combine 16 tile-partials for this tile's rows & cols ----
    if (t < 64) {
        const float* base = rowp + 2 * ((size_t)(x0 + t) * 16);
        float2 p = load_f2(base);
        float m = p.x, l = p.y;
        #pragma unroll
        for (int k = 1; k < 16; ++k) {
            float2 q = load_f2(base + 2 * k);
            float nm = fmaxf(m, q.x);
            l = l * __expf(m - nm) + q.y * __expf(q.x - nm);
            m = nm;
        }
        rm_s[t] = m; rl_s[t] = 1.f / l;
    } else if (t < 128) {
        const float* base = colp + 2 * ((size_t)(y0 + (t - 64)) * 16);
        float2 p = load_f2(base);
        float m = p.x, l = p.y;
        #pragma unroll
        for (int k = 1; k < 16; ++k) {
            float2 q = load_f2(base + 2 * k);
            float nm = fmaxf(m, q.x);
            l = l * __expf(m - nm) + q.y * __expf(q.x - nm);
            m = nm;
        }
        cm_s[t - 64] = m; cl_s[t - 64] = 1.f / l;
    }
    __syncthreads();

    // ---- Phase 3: weighted reduction from registers ----
    float S0 = 0.f, S1 = 0.f;
    #pragma unroll
    for (int i = 0; i < 2; ++i) {
        const float rm = rm_s[2 * ty + i];
        const float rl = rl_s[2 * ty + i];
        #pragma unroll
        for (int j = 0; j < 4; ++j) {
            const float cm = cm_s[4 * tx + j];
            const float cl = cl_s[4 * tx + j];
            float s = sv[i][j];
            float a = __expf(s - rm) * rl;
            float b = __expf(s - cm) * cl;
            float w = a + b - a * b;
            S0 += w;
            S1 += w * s;
        }
    }
    #pragma unroll
    for (int off = 32; off; off >>= 1) {
        S0 += __shfl_xor(S0, off, 64);
        S1 += __shfl_xor(S1, off, 64);
    }
    {
        const int wave = t >> 6, lane = t & 63;
        if (lane == 0) { red0[wave] = S0; red1[wave] = S1; }
    }
    __syncthreads();
    if (t == 0) {
        float t0 = 0.f, t1 = 0.f;
        #pragma unroll
        for (int w = 0; w < 8; ++w) { t0 += red0[w]; t1 += red1[w]; }
        store_f2(part + 2 * blockIdx.x, t0, t1);
        __hip_atomic_store(&flag2[blockIdx.x], 1, __ATOMIC_RELEASE, __HIP_MEMORY_SCOPE_AGENT);
    }

    // ---- Finalize: only block 0 waits on flag2, sums parts, writes out ----
    if (blockIdx.x == 0) {
        if (t < NBLK) {
            while (__hip_atomic_load(&flag2[t], __ATOMIC_RELAXED, __HIP_MEMORY_SCOPE_AGENT) != 1)
                __builtin_amdgcn_s_sleep(8);
        }
        __threadfence();
        __syncthreads();

        float S0f = 0.f, S1f = 0.f;
        if (t < NBLK) {
            float2 p = load_f2(part + 2 * t);
            S0f = p.x; S1f = p.y;
        }
        #pragma unroll
        for (int off = 32; off; off >>= 1) {
            S0f += __shfl_xor(S0f, off, 64);
            S1f += __shfl_xor(S1f, off, 64);
        }
        {
            const int wave = t >> 6, lane = t & 63;
            if (lane == 0) { red0[wave] = S0f; red1[wave] = S1f; }
        }
        __syncthreads();
        if (t < NCM1) {
            float t0 = red0[0] + red0[1] + red0[2] + red0[3];
            float t1 = red1[0] + red1[1] + red1[2] + red1[3];
            float c = t1 / t0;
            out[t] = c * theta[t] + beta[t];
        }
    }
}

// -------------------------------------------------------------------------
extern "C" void kernel_launch(void* const* d_in, const int* in_sizes, int n_in,
                              void* d_out, int out_size, void* d_ws, size_t ws_size,
                              hipStream_t stream)
{
    const float* zx    = (const float*)d_in[0];
    const float* zy    = (const float*)d_in[1];
    const float* theta = (const float*)d_in[2];
    const float* beta  = (const float*)d_in[3];
    float* out = (float*)d_out;
    float* ws  = (float*)d_ws;

    fused_kernel<<<NBLK, 512, 0, stream>>>(zx, zy, theta, beta, ws, out);
}

// Round 6
// 77.154 us; speedup vs baseline: 1.7790x; 1.4952x over previous
//
#include <hip/hip_runtime.h>
#include <math.h>

// Problem constants (match reference)
#define NXC 1024
#define NYC 1024
#define DC  128
#define NCM1 4
#define NBLK 256   // 16x16 tiles of 64x64

// ws float offsets
#define WS_STILE 0          // 256 blocks * 4096 floats (64x64 f32 s-tiles) = 4 MB
#define WS_ROWP  1048576    // float2[1024][16] (m,l) row partials -> 32768 floats
#define WS_COLP  1081344    // float2[1024][16] (m,l) col partials -> 32768 floats
#define WS_PART  1114112    // float2[256] (S0,S1) block partials  ->   512 floats

typedef _Float16 half2v __attribute__((ext_vector_type(2)));
union H2U { half2v h; unsigned u; };

#if defined(__has_builtin)
#if __has_builtin(__builtin_amdgcn_fdot2)
#define HAVE_FDOT2 1
#endif
#endif

// |xa - ya| summed into f32 acc, 8 halves (one 16B chunk) at a time.
__device__ __forceinline__ float absdiff_dot(uint4 xa, uint4 ya, float acc)
{
    const unsigned* xu = (const unsigned*)&xa;
    const unsigned* yu = (const unsigned*)&ya;
    half2v one; one.x = (_Float16)1.f; one.y = (_Float16)1.f;
    #pragma unroll
    for (int q = 0; q < 4; ++q) {
        H2U x, y, d;
        x.u = xu[q]; y.u = yu[q];
        d.h = x.h - y.h;              // v_pk_add_f16 (neg)
        d.u &= 0x7FFF7FFFu;           // packed abs
#ifdef HAVE_FDOT2
        acc = __builtin_amdgcn_fdot2(d.h, one, acc, false);  // v_dot2_f32_f16
#else
        acc += (float)d.h.x + (float)d.h.y;
#endif
    }
    return acc;
}

// -------------------------------------------------------------------------
// Kernel A: 256 blocks (64x64 tile each) x 512 threads. fp16 staged LDS,
// 2x4 micro-tile per thread. Outputs: s-tile (f32, thread-contiguous layout
// shared with kernel B), per-tile row partials, per-tile col partials.
// Plain stores only — the kernel boundary is the grid barrier.
// -------------------------------------------------------------------------
__global__ __launch_bounds__(512, 2) void distance_kernel(
    const float* __restrict__ zx, const float* __restrict__ zy,
    float* __restrict__ ws)
{
    __shared__ __align__(16) _Float16 xs[64 * 128];
    __shared__ __align__(16) _Float16 ys[64 * 128];
    __shared__ float cpm[32][64], cpl[32][64];

    float* stile = ws + WS_STILE;
    float* rowp  = ws + WS_ROWP;
    float* colp  = ws + WS_COLP;

    const int t  = threadIdx.x;
    const int bx = blockIdx.x & 15;   // col-tile index
    const int by = blockIdx.x >> 4;   // row-tile index
    const int x0 = by * 64;
    const int y0 = bx * 64;

    // ---- stage 64x128 of zx, zy into LDS as fp16 (RNE casts) ----
    #pragma unroll
    for (int k = 0; k < 2; ++k) {
        int idx = t + k * 512;        // half8-chunk index: 64 rows x 16 chunks
        int r   = idx >> 4;
        int j   = idx & 15;
        int off = r * 128 + 8 * (j ^ ((r >> 2) & 7));

        const float4* gx = (const float4*)(zx + (size_t)(x0 + r) * DC + 8 * j);
        float4 xv0 = gx[0], xv1 = gx[1];
        const float4* gy = (const float4*)(zy + (size_t)(y0 + r) * DC + 8 * j);
        float4 yv0 = gy[0], yv1 = gy[1];

        uint4 hx, hy;
        {
            H2U a, b, c, d;
            a.h.x = (_Float16)xv0.x; a.h.y = (_Float16)xv0.y;
            b.h.x = (_Float16)xv0.z; b.h.y = (_Float16)xv0.w;
            c.h.x = (_Float16)xv1.x; c.h.y = (_Float16)xv1.y;
            d.h.x = (_Float16)xv1.z; d.h.y = (_Float16)xv1.w;
            hx.x = a.u; hx.y = b.u; hx.z = c.u; hx.w = d.u;
            a.h.x = (_Float16)yv0.x; a.h.y = (_Float16)yv0.y;
            b.h.x = (_Float16)yv0.z; b.h.y = (_Float16)yv0.w;
            c.h.x = (_Float16)yv1.x; c.h.y = (_Float16)yv1.y;
            d.h.x = (_Float16)yv1.z; d.h.y = (_Float16)yv1.w;
            hy.x = a.u; hy.y = b.u; hy.z = c.u; hy.w = d.u;
        }
        *(uint4*)(xs + off) = hx;
        *(uint4*)(ys + off) = hy;
    }
    __syncthreads();

    const int tx = t & 15;            // 4 cols each
    const int ty = t >> 4;            // 0..31, 2 rows each
    const int xswz = (ty >> 1) & 7;
    const int yswz = tx & 7;

    const _Float16* xb = xs + (2 * ty) * 128;
    const _Float16* yb = ys + (4 * tx) * 128;

    // ---- 2x4 micro-tile L1 distances, distance-1 prefetch ----
    float acc[2][4];
    #pragma unroll
    for (int i = 0; i < 2; ++i)
        #pragma unroll
        for (int j = 0; j < 4; ++j) acc[i][j] = 0.f;

    uint4 xc0 = *(const uint4*)(xb +       8 * (0 ^ xswz));
    uint4 xc1 = *(const uint4*)(xb + 128 + 8 * (0 ^ xswz));
    uint4 yc0 = *(const uint4*)(yb +       8 * (0 ^ yswz));
    uint4 yc1 = *(const uint4*)(yb + 128 + 8 * (0 ^ yswz));
    uint4 yc2 = *(const uint4*)(yb + 256 + 8 * (0 ^ yswz));
    uint4 yc3 = *(const uint4*)(yb + 384 + 8 * (0 ^ yswz));

    #pragma unroll 4
    for (int j = 0; j < 16; ++j) {
        uint4 xa0 = xc0, xa1 = xc1, ya0 = yc0, ya1 = yc1, ya2 = yc2, ya3 = yc3;
        if (j < 15) {
            const int jn = j + 1;
            xc0 = *(const uint4*)(xb +       8 * (jn ^ xswz));
            xc1 = *(const uint4*)(xb + 128 + 8 * (jn ^ xswz));
            yc0 = *(const uint4*)(yb +       8 * (jn ^ yswz));
            yc1 = *(const uint4*)(yb + 128 + 8 * (jn ^ yswz));
            yc2 = *(const uint4*)(yb + 256 + 8 * (jn ^ yswz));
            yc3 = *(const uint4*)(yb + 384 + 8 * (jn ^ yswz));
        }
        acc[0][0] = absdiff_dot(xa0, ya0, acc[0][0]);
        acc[0][1] = absdiff_dot(xa0, ya1, acc[0][1]);
        acc[0][2] = absdiff_dot(xa0, ya2, acc[0][2]);
        acc[0][3] = absdiff_dot(xa0, ya3, acc[0][3]);
        acc[1][0] = absdiff_dot(xa1, ya0, acc[1][0]);
        acc[1][1] = absdiff_dot(xa1, ya1, acc[1][1]);
        acc[1][2] = absdiff_dot(xa1, ya2, acc[1][2]);
        acc[1][3] = absdiff_dot(xa1, ya3, acc[1][3]);
    }

    float sv[2][4];
    #pragma unroll
    for (int i = 0; i < 2; ++i)
        #pragma unroll
        for (int j = 0; j < 4; ++j) sv[i][j] = -acc[i][j];

    // ---- store s-tile (thread-contiguous, reread identically by kernel B) ----
    {
        float* sb = stile + (size_t)blockIdx.x * 4096 + t * 8;
        *(float4*)(sb)     = make_float4(sv[0][0], sv[0][1], sv[0][2], sv[0][3]);
        *(float4*)(sb + 4) = make_float4(sv[1][0], sv[1][1], sv[1][2], sv[1][3]);
    }

    // ---- per-tile ROW partials (merge across tx, in-wave) ----
    #pragma unroll
    for (int i = 0; i < 2; ++i) {
        float m = fmaxf(fmaxf(sv[i][0], sv[i][1]), fmaxf(sv[i][2], sv[i][3]));
        float l = __expf(sv[i][0] - m) + __expf(sv[i][1] - m)
                + __expf(sv[i][2] - m) + __expf(sv[i][3] - m);
        #pragma unroll
        for (int off = 1; off < 16; off <<= 1) {
            float mo = __shfl_xor(m, off, 64);
            float lo = __shfl_xor(l, off, 64);
            float nm = fmaxf(m, mo);
            l = l * __expf(m - nm) + lo * __expf(mo - nm);
            m = nm;
        }
        if (tx == 0)
            *(float2*)(rowp + 2 * ((size_t)(x0 + 2 * ty + i) * 16 + bx)) = make_float2(m, l);
    }

    // ---- per-tile COL partials (merge across ty via LDS) ----
    #pragma unroll
    for (int j = 0; j < 4; ++j) {
        float m = fmaxf(sv[0][j], sv[1][j]);
        float l = __expf(sv[0][j] - m) + __expf(sv[1][j] - m);
        cpm[ty][4 * tx + j] = m;
        cpl[ty][4 * tx + j] = l;
    }
    __syncthreads();
    if (t < 64) {
        float m = cpm[0][t], l = cpl[0][t];
        #pragma unroll 8
        for (int k = 1; k < 32; ++k) {
            float mo = cpm[k][t], lo = cpl[k][t];
            float nm = fmaxf(m, mo);
            l = l * __expf(m - nm) + lo * __expf(mo - nm);
            m = nm;
        }
        *(float2*)(colp + 2 * ((size_t)(y0 + t) * 16 + by)) = make_float2(m, l);
    }
}

// -------------------------------------------------------------------------
// Kernel B: same grid/tile mapping. Combine the 16 row/col partials for this
// tile, reload the s-tile, accumulate S0/S1, one float2 partial per block.
// -------------------------------------------------------------------------
__global__ __launch_bounds__(512, 2) void reduce_kernel(
    const float* __restrict__ ws_in, float* __restrict__ ws_out)
{
    __shared__ float rm_s[64], rl_s[64], cm_s[64], cl_s[64];
    __shared__ float red0[8], red1[8];

    const float* stile = ws_in + WS_STILE;
    const float* rowp  = ws_in + WS_ROWP;
    const float* colp  = ws_in + WS_COLP;
    float* part = ws_out + WS_PART;

    const int t  = threadIdx.x;
    const int bx = blockIdx.x & 15;
    const int by = blockIdx.x >> 4;
    const int x0 = by * 64;
    const int y0 = bx * 64;

    if (t < 64) {
        const float2* base = (const float2*)(rowp) + (size_t)(x0 + t) * 16;
        float2 p = base[0];
        float m = p.x, l = p.y;
        #pragma unroll
        for (int k = 1; k < 16; ++k) {
            float2 q = base[k];
            float nm = fmaxf(m, q.x);
            l = l * __expf(m - nm) + q.y * __expf(q.x - nm);
            m = nm;
        }
        rm_s[t] = m; rl_s[t] = 1.f / l;
    } else if (t < 128) {
        const float2* base = (const float2*)(colp) + (size_t)(y0 + (t - 64)) * 16;
        float2 p = base[0];
        float m = p.x, l = p.y;
        #pragma unroll
        for (int k = 1; k < 16; ++k) {
            float2 q = base[k];
            float nm = fmaxf(m, q.x);
            l = l * __expf(m - nm) + q.y * __expf(q.x - nm);
            m = nm;
        }
        cm_s[t - 64] = m; cl_s[t - 64] = 1.f / l;
    }
    __syncthreads();

    const int tx = t & 15;
    const int ty = t >> 4;

    const float* sb = stile + (size_t)blockIdx.x * 4096 + t * 8;
    float4 s0 = ((const float4*)sb)[0];
    float4 s1 = ((const float4*)sb)[1];
    float sv[2][4] = {{s0.x, s0.y, s0.z, s0.w}, {s1.x, s1.y, s1.z, s1.w}};

    float S0 = 0.f, S1 = 0.f;
    #pragma unroll
    for (int i = 0; i < 2; ++i) {
        const float rm = rm_s[2 * ty + i];
        const float rl = rl_s[2 * ty + i];
        #pragma unroll
        for (int j = 0; j < 4; ++j) {
            const float cm = cm_s[4 * tx + j];
            const float cl = cl_s[4 * tx + j];
            float s = sv[i][j];
            float a = __expf(s - rm) * rl;
            float b = __expf(s - cm) * cl;
            float w = a + b - a * b;
            S0 += w;
            S1 += w * s;
        }
    }
    #pragma unroll
    for (int off = 32; off; off >>= 1) {
        S0 += __shfl_xor(S0, off, 64);
        S1 += __shfl_xor(S1, off, 64);
    }
    {
        const int wave = t >> 6, lane = t & 63;
        if (lane == 0) { red0[wave] = S0; red1[wave] = S1; }
    }
    __syncthreads();
    if (t == 0) {
        float t0 = 0.f, t1 = 0.f;
        #pragma unroll
        for (int w = 0; w < 8; ++w) { t0 += red0[w]; t1 += red1[w]; }
        *(float2*)(part + 2 * blockIdx.x) = make_float2(t0, t1);
    }
}

// -------------------------------------------------------------------------
// Kernel C: sum 256 block partials, write the 4 logits.
// -------------------------------------------------------------------------
__global__ __launch_bounds__(256) void finalize_kernel(
    const float* __restrict__ ws,
    const float* __restrict__ theta, const float* __restrict__ beta,
    float* __restrict__ out)
{
    __shared__ float red0[4], red1[4];
    const float* part = ws + WS_PART;
    const int t = threadIdx.x;

    float2 p = ((const float2*)part)[t];
    float S0 = p.x, S1 = p.y;
    #pragma unroll
    for (int off = 32; off; off >>= 1) {
        S0 += __shfl_xor(S0, off, 64);
        S1 += __shfl_xor(S1, off, 64);
    }
    const int wave = t >> 6, lane = t & 63;
    if (lane == 0) { red0[wave] = S0; red1[wave] = S1; }
    __syncthreads();
    if (t < NCM1) {
        float t0 = red0[0] + red0[1] + red0[2] + red0[3];
        float t1 = red1[0] + red1[1] + red1[2] + red1[3];
        float c = t1 / t0;
        out[t] = c * theta[t] + beta[t];
    }
}

// -------------------------------------------------------------------------
extern "C" void kernel_launch(void* const* d_in, const int* in_sizes, int n_in,
                              void* d_out, int out_size, void* d_ws, size_t ws_size,
                              hipStream_t stream)
{
    const float* zx    = (const float*)d_in[0];
    const float* zy    = (const float*)d_in[1];
    const float* theta = (const float*)d_in[2];
    const float* beta  = (const float*)d_in[3];
    float* out = (float*)d_out;
    float* ws  = (float*)d_ws;

    distance_kernel<<<NBLK, 512, 0, stream>>>(zx, zy, ws);
    reduce_kernel<<<NBLK, 512, 0, stream>>>(ws, ws);
    finalize_kernel<<<1, 256, 0, stream>>>(ws, theta, beta, out);
}